// Round 7
// baseline (691.262 us; speedup 1.0000x reference)
//
#include <hip/hip_runtime.h>
#include <math.h>

#define BB 4
#define TT 8192
#define EE 8
#define HH 1024
#define HPD 128
#define KSEL 1024
#define QW 384   // 3*HP

typedef __attribute__((ext_vector_type(8))) short s16x8;
typedef __attribute__((ext_vector_type(4))) float f32x4;

// ---- workspace layout (bytes) ----
#define OFF_L    ((size_t)0)                                   // float[B*T*E]          1 MB
#define OFF_IDX  (OFF_L    + (size_t)BB*TT*EE*4)               // int[B*E*K]            128 KB
#define OFF_GATE (OFF_IDX  + (size_t)BB*EE*KSEL*4)             // float[B*E*K]          128 KB
#define OFF_TRIG (OFF_GATE + (size_t)BB*EE*KSEL*4)             // float2[8192*32]       2 MB
#define OFF_QH   (OFF_TRIG + (size_t)TT*32*8)                  // bf16[B*E*K*128]       8 MB
#define OFF_QL   (OFF_QH   + (size_t)BB*EE*KSEL*HPD*2)
#define OFF_KH   (OFF_QL   + (size_t)BB*EE*KSEL*HPD*2)
#define OFF_KL   (OFF_KH   + (size_t)BB*EE*KSEL*HPD*2)
#define OFF_VT   (OFF_KL   + (size_t)BB*EE*KSEL*HPD*2)         // bf16[B*E*128*K] transposed
#define OFF_AVH  (OFF_VT   + (size_t)BB*EE*KSEL*HPD*2)         // bf16[B*E*K*128]       8 MB
#define OFF_AVL  (OFF_AVH  + (size_t)BB*EE*KSEL*HPD*2)         // bf16[B*E*K*128]       8 MB
#define OFF_WTH  (OFF_AVL  + (size_t)BB*EE*KSEL*HPD*2)         // bf16[E][384][1024]    6.3 MB
#define OFF_WTL  (OFF_WTH  + (size_t)EE*QW*HH*2)
#define OFF_WOH  (OFF_WTL  + (size_t)EE*QW*HH*2)               // bf16[E][1024][128]    2 MB
#define OFF_WOL  (OFF_WOH  + (size_t)EE*HH*HPD*2)

static __device__ inline unsigned short f2bf(float x) {        // fp32 -> bf16 bits, RNE
    unsigned u = __float_as_uint(x);
    return (unsigned short)((u + 0x7fffu + ((u >> 16) & 1u)) >> 16);
}
static __device__ inline float bf2f(unsigned short h) {
    return __uint_as_float((unsigned)h << 16);
}
static __device__ inline unsigned cvtpk(float lo, float hi) {  // packed 2xf32 -> 2xbf16
    unsigned r;
    asm("v_cvt_pk_bf16_f32 %0, %1, %2" : "=v"(r) : "v"(lo), "v"(hi));
    return r;
}
static __device__ inline f32x4 mfma16(s16x8 a, s16x8 b, f32x4 c) {
    return __builtin_amdgcn_mfma_f32_16x16x32_bf16(a, b, c, 0, 0, 0);
}

// ---------------- 0. trig table ----------------
__global__ __launch_bounds__(256) void trig_kernel(float2* __restrict__ trig) {
    int i = blockIdx.x * 256 + threadIdx.x;      // i < 8192*32
    int pos = i >> 5, j = i & 31;
    double inv = pow(10000.0, -(double)(2 * j) / 64.0);
    double a = (double)pos * inv;
    trig[i] = make_float2((float)cos(a), (float)sin(a));
}

// ---------------- 0b. Wqkv prep: [e][k][n] -> [e][n][k], bf16 hi/lo ----------------
__global__ __launch_bounds__(256) void wprep_kernel(const float* __restrict__ Wqkv,
                                                    unsigned short* __restrict__ Wth,
                                                    unsigned short* __restrict__ Wtl) {
    __shared__ float t[32][33];
    int kt = blockIdx.x, nt = blockIdx.y, e = blockIdx.z;
    int lx = threadIdx.x & 31, ly = threadIdx.x >> 5;         // 32 x 8
    const float* src = Wqkv + (size_t)e * HH * QW;
#pragma unroll
    for (int i = 0; i < 4; i++) {
        int yy = ly + i * 8;
        t[yy][lx] = src[(size_t)(kt * 32 + yy) * QW + nt * 32 + lx];
    }
    __syncthreads();
#pragma unroll
    for (int i = 0; i < 4; i++) {
        int yy = ly + i * 8;                                   // n within tile
        float v = t[lx][yy];
        unsigned short h = f2bf(v);
        unsigned short l = f2bf(v - bf2f(h));
        size_t o = ((size_t)e * QW + nt * 32 + yy) * HH + kt * 32 + lx;
        Wth[o] = h;
        Wtl[o] = l;
    }
}

// ---------------- 0c. Wo prep: [e][k=128][n=1024] -> [e][n][k], bf16 hi/lo ----------------
__global__ __launch_bounds__(256) void wo_prep_kernel(const float* __restrict__ Wo,
                                                      unsigned short* __restrict__ Woh,
                                                      unsigned short* __restrict__ Wol) {
    __shared__ float t[32][33];
    int kt = blockIdx.x, nt = blockIdx.y, e = blockIdx.z;     // kt<4, nt<32
    int lx = threadIdx.x & 31, ly = threadIdx.x >> 5;
    const float* src = Wo + (size_t)e * HPD * HH;
#pragma unroll
    for (int i = 0; i < 4; i++) {
        int yy = ly + i * 8;
        t[yy][lx] = src[(size_t)(kt * 32 + yy) * HH + nt * 32 + lx];
    }
    __syncthreads();
#pragma unroll
    for (int i = 0; i < 4; i++) {
        int yy = ly + i * 8;                                   // n within tile
        float v = t[lx][yy];
        unsigned short h = f2bf(v);
        unsigned short l = f2bf(v - bf2f(h));
        size_t o = ((size_t)e * HH + nt * 32 + yy) * HPD + kt * 32 + lx;
        Woh[o] = h;
        Wol[o] = l;
    }
}

// ---------------- 1. router ----------------
__global__ __launch_bounds__(256) void router_kernel(const float* __restrict__ X,
                                                     const float* __restrict__ Wr,
                                                     float* __restrict__ L) {
    __shared__ float wr_s[EE * HH];
    int tid = threadIdx.x;
    for (int i = tid; i < EE * HH; i += 256) wr_s[i] = Wr[i];
    __syncthreads();
    int wave = tid >> 6, lane = tid & 63;
    int row = blockIdx.x * 4 + wave;
    const float* xr = X + (size_t)row * HH;
    double acc[EE];
#pragma unroll
    for (int e = 0; e < EE; e++) acc[e] = 0.0;
#pragma unroll
    for (int it = 0; it < 4; it++) {
        int d0 = it * 256 + lane * 4;
        float4 x4 = *(const float4*)(xr + d0);
#pragma unroll
        for (int e = 0; e < EE; e++) {
            float4 w4 = *(const float4*)(wr_s + e * HH + d0);
            acc[e] += (double)x4.x * w4.x + (double)x4.y * w4.y +
                      (double)x4.z * w4.z + (double)x4.w * w4.w;
        }
    }
#pragma unroll
    for (int off = 32; off > 0; off >>= 1)
#pragma unroll
        for (int e = 0; e < EE; e++) acc[e] += __shfl_xor(acc[e], off, 64);
    if (lane < EE) L[(size_t)row * EE + lane] = (float)acc[lane];
}

// ---------------- 2. top-k (bitonic) then re-sort selected by index ASC ----------------
__global__ __launch_bounds__(1024) void topk_kernel(const float* __restrict__ L,
                                                    int* __restrict__ topk_idx,
                                                    float* __restrict__ gate) {
    __shared__ unsigned long long s[TT];          // 64 KB
    int be = blockIdx.x, b = be >> 3, e = be & 7;
    int tid = threadIdx.x;
    for (int t = tid; t < TT; t += 1024) {
        float v = L[((size_t)b * TT + t) * EE + e];
        unsigned u = __float_as_uint(v);
        u ^= (u >> 31) ? 0xFFFFFFFFu : 0x80000000u;
        unsigned inv = ~u;
        s[t] = ((unsigned long long)inv << 32) | (unsigned)t;
    }
    __syncthreads();
    for (int size = 2; size <= TT; size <<= 1) {
        for (int stride = size >> 1; stride > 0; stride >>= 1) {
            for (int t = tid; t < TT / 2; t += 1024) {
                int j = t & (stride - 1);
                int lo = ((t ^ j) << 1) | j;
                int hi = lo + stride;
                unsigned long long a = s[lo], c = s[hi];
                bool asc = ((lo & size) == 0);
                if ((a > c) == asc) { s[lo] = c; s[hi] = a; }
            }
            __syncthreads();
        }
    }
    unsigned long long key = 0;
    if (tid < KSEL) {
        int idx = (int)(unsigned)s[tid];
        float v = L[((size_t)b * TT + idx) * EE + e];
        float g = 1.0f / (1.0f + expf(-v));
        key = ((unsigned long long)(unsigned)idx << 32) | __float_as_uint(g);
    }
    __syncthreads();
    if (tid < KSEL) s[tid] = key;
    __syncthreads();
    for (int size = 2; size <= KSEL; size <<= 1) {
        for (int stride = size >> 1; stride > 0; stride >>= 1) {
            int t = tid;
            if (t < KSEL / 2) {
                int j = t & (stride - 1);
                int lo = ((t ^ j) << 1) | j;
                int hi = lo + stride;
                unsigned long long a = s[lo], c = s[hi];
                bool asc = ((lo & size) == 0);
                if ((a > c) == asc) { s[lo] = c; s[hi] = a; }
            }
            __syncthreads();
        }
    }
    if (tid < KSEL) {
        topk_idx[be * KSEL + tid] = (int)(s[tid] >> 32);
        gate[be * KSEL + tid] = __uint_as_float((unsigned)s[tid]);
    }
}

// ---------------- 3. QKV GEMM via MFMA bf16 hi/lo 3-pass + fused RoPE ----------------
// 128x128 tile, BK=64, 512 threads = 8 waves in 4(row)x2(col) grid; each wave 32x64.
// waves_per_eu PINNED to (4,4): LDS (74 KB -> 2 blocks/CU) caps occupancy at 4 waves/EU;
// an open-ended range makes the allocator spill to chase 8 waves/EU (r2/r5/r6: 316 MB
// scratch writes). Pinning gives the 128-VGPR budget the ~95-reg demand actually needs.
#define LDA 72   // 144 B rows = 9 x 16 B
__global__ __launch_bounds__(512)
__attribute__((amdgpu_waves_per_eu(4, 4)))
void qkv_kernel(const float* __restrict__ X,
                const unsigned short* __restrict__ Wth,
                const unsigned short* __restrict__ Wtl,
                const int* __restrict__ topk_idx,
                const float2* __restrict__ trig,
                unsigned short* __restrict__ Qh,
                unsigned short* __restrict__ Ql,
                unsigned short* __restrict__ Kh,
                unsigned short* __restrict__ Kl,
                unsigned short* __restrict__ Vt) {
    __shared__ __align__(16) unsigned short smem[4 * 128 * LDA];   // 73728 B
    __shared__ int rows_s[128];
    unsigned short* Ah = smem;                  // [128][72]
    unsigned short* Al = smem + 128 * LDA;
    unsigned short* Bh = smem + 2 * 128 * LDA;  // [128 n][72 k]
    unsigned short* Bl = smem + 3 * 128 * LDA;
    int tid = threadIdx.x;
    int w = tid >> 6, lane = tid & 63, ln = lane & 15, quad = lane >> 4;
    int wm = w >> 1, wn = w & 1;                // wm<4 (32-row strips), wn<2 (64-col strips)
    int mt = blockIdx.x, nt = blockIdx.y, be = blockIdx.z;
    int b = be >> 3, e = be & 7;
    if (tid < 128) rows_s[tid] = topk_idx[be * KSEL + mt * 128 + tid];
    __syncthreads();

    f32x4 acc[2][4];
#pragma unroll
    for (int mf = 0; mf < 2; mf++)
#pragma unroll
        for (int nf = 0; nf < 4; nf++) acc[mf][nf] = (f32x4){0.f, 0.f, 0.f, 0.f};

    const float* xb = X + (size_t)b * TT * HH;
    const unsigned short* wbh = Wth + ((size_t)e * QW + nt * 128) * HH;
    const unsigned short* wbl = Wtl + ((size_t)e * QW + nt * 128) * HH;
    int ar = tid >> 2, aq = tid & 3;                  // A: row, 16-col quarter
    const float* asrc = xb + (size_t)rows_s[ar] * HH + aq * 16;

    float4 aR[4];
    uint4 bR[4];
#define QKV_LOAD(K0)                                                                     \
    {                                                                                    \
        _Pragma("unroll") for (int i = 0; i < 4; i++)                                    \
            aR[i] = *(const float4*)(asrc + (K0) + i * 4);                               \
        _Pragma("unroll") for (int s = 0; s < 4; s++) {                                  \
            int c = s * 512 + tid;                                                       \
            int buf = c >> 10, idx = c & 1023;                                           \
            int row = idx >> 3, seg = idx & 7;                                           \
            const unsigned short* sp = (buf ? wbl : wbh) +                               \
                (size_t)row * HH + (K0) + seg * 8;                                       \
            bR[s] = *(const uint4*)sp;                                                   \
        }                                                                                \
    }
    QKV_LOAD(0);
    for (int k0 = 0; k0 < HH; k0 += 64) {
        // convert A regs -> hi/lo LDS (16 fp32 per thread)
        {
            unsigned short* dh = Ah + ar * LDA + aq * 16;
            unsigned short* dl = Al + ar * LDA + aq * 16;
#pragma unroll
            for (int i = 0; i < 2; i++) {
                float4 x = aR[2 * i], y = aR[2 * i + 1];
                unsigned h0 = cvtpk(x.x, x.y), h1 = cvtpk(x.z, x.w);
                unsigned h2 = cvtpk(y.x, y.y), h3 = cvtpk(y.z, y.w);
                float l0 = x.x - __uint_as_float(h0 << 16);
                float l1 = x.y - __uint_as_float(h0 & 0xffff0000u);
                float l2 = x.z - __uint_as_float(h1 << 16);
                float l3 = x.w - __uint_as_float(h1 & 0xffff0000u);
                float l4 = y.x - __uint_as_float(h2 << 16);
                float l5 = y.y - __uint_as_float(h2 & 0xffff0000u);
                float l6 = y.z - __uint_as_float(h3 << 16);
                float l7 = y.w - __uint_as_float(h3 & 0xffff0000u);
                *(uint4*)(dh + i * 8) = make_uint4(h0, h1, h2, h3);
                *(uint4*)(dl + i * 8) = make_uint4(cvtpk(l0, l1), cvtpk(l2, l3),
                                                   cvtpk(l4, l5), cvtpk(l6, l7));
            }
            // B regs -> LDS
#pragma unroll
            for (int s = 0; s < 4; s++) {
                int c = s * 512 + tid;
                int buf = c >> 10, idx = c & 1023;
                int row = idx >> 3, seg = idx & 7;
                unsigned short* dst = (buf ? Bl : Bh) + row * LDA + seg * 8;
                *(uint4*)dst = bR[s];
            }
        }
        __syncthreads();
        if (k0 < HH - 64) QKV_LOAD(k0 + 64);          // in flight during MFMA
#pragma unroll
        for (int kk = 0; kk < 2; kk++) {
            s16x8 a_h[2], a_l[2];
#pragma unroll
            for (int mf = 0; mf < 2; mf++) {
                const unsigned short* p = Ah + (wm * 32 + mf * 16 + ln) * LDA + kk * 32 + quad * 8;
                a_h[mf] = *(const s16x8*)p;
                a_l[mf] = *(const s16x8*)(p + 128 * LDA);
            }
#pragma unroll
            for (int nf = 0; nf < 4; nf++) {
                const unsigned short* p = Bh + (wn * 64 + nf * 16 + ln) * LDA + kk * 32 + quad * 8;
                s16x8 b_h = *(const s16x8*)p;
                s16x8 b_l = *(const s16x8*)(p + 128 * LDA);
#pragma unroll
                for (int mf = 0; mf < 2; mf++) {
                    acc[mf][nf] = mfma16(a_h[mf], b_h, acc[mf][nf]);
                    acc[mf][nf] = mfma16(a_l[mf], b_h, acc[mf][nf]);
                    acc[mf][nf] = mfma16(a_h[mf], b_l, acc[mf][nf]);
                }
            }
        }
        __syncthreads();
    }

    if (nt < 2) {
        // RoPE: cols 0..63 live in wn==0 waves; pair (j, j+32) = frags (nf, nf+2), lane-local
        if (wn == 0) {
#pragma unroll
            for (int mf = 0; mf < 2; mf++)
#pragma unroll
                for (int r = 0; r < 4; r++) {
                    int pos = rows_s[wm * 32 + mf * 16 + quad * 4 + r];
#pragma unroll
                    for (int nf = 0; nf < 2; nf++) {
                        int j = nf * 16 + ln;
                        float2 sc = trig[pos * 32 + j];
                        float own = acc[mf][nf][r], oth = acc[mf][nf + 2][r];
                        acc[mf][nf][r]     = own * sc.x - oth * sc.y;
                        acc[mf][nf + 2][r] = oth * sc.x + own * sc.y;
                    }
                }
        }
        float qs = (nt == 0) ? 0.08838834764831845f : 1.0f;
        unsigned short* Ph = (nt == 0) ? Qh : Kh;
        unsigned short* Pl = (nt == 0) ? Ql : Kl;
#pragma unroll
        for (int mf = 0; mf < 2; mf++)
#pragma unroll
            for (int r = 0; r < 4; r++) {
                int rowg = mt * 128 + wm * 32 + mf * 16 + quad * 4 + r;
                size_t rb = ((size_t)be * KSEL + rowg) * HPD;
#pragma unroll
                for (int nf = 0; nf < 4; nf++) {
                    int col = wn * 64 + nf * 16 + ln;
                    float x = acc[mf][nf][r] * qs;
                    unsigned short h = f2bf(x);
                    Ph[rb + col] = h;
                    Pl[rb + col] = f2bf(x - bf2f(h));
                }
            }
    } else {
        // V: transpose 128x128 through LDS (reuse staging region), write Vt coalesced
        unsigned short* T = smem;                 // [128 d][136 m]
#pragma unroll
        for (int mf = 0; mf < 2; mf++)
#pragma unroll
            for (int nf = 0; nf < 4; nf++)
#pragma unroll
                for (int r = 0; r < 4; r++)
                    T[(wn * 64 + nf * 16 + ln) * 136 + wm * 32 + mf * 16 + quad * 4 + r] =
                        f2bf(acc[mf][nf][r]);
        __syncthreads();
        for (int j = tid; j < 2048; j += 512) {
            int d = j >> 4, mseg = j & 15;
            uint4 v = *(uint4*)&T[d * 136 + mseg * 8];
            *(uint4*)(Vt + ((size_t)be * HPD + d) * KSEL + mt * 128 + mseg * 8) = v;
        }
    }
}

// ---------------- 4. causal flash attention, MFMA 16x16x32 bf16 ----------------
// LDS 62.5 KB -> 2 blocks/CU = 2 waves/EU; pin it so the allocator doesn't spill
// the O/Q register state chasing unreachable occupancy.
__global__ __launch_bounds__(256)
__attribute__((amdgpu_waves_per_eu(2, 2)))
void attn_kernel(const unsigned short* __restrict__ Qh,
                 const unsigned short* __restrict__ Ql,
                 const unsigned short* __restrict__ Kh,
                 const unsigned short* __restrict__ Kl,
                 const unsigned short* __restrict__ Vt,
                 const float* __restrict__ gate,
                 unsigned short* __restrict__ AVh,
                 unsigned short* __restrict__ AVl) {
    __shared__ __align__(16) unsigned short sm[31232];  // 62464 B
    unsigned short* sKH = sm;                 // [64][136]
    unsigned short* sKL = sm + 8704;          // [64][136]
    unsigned short* sVT = sm + 17408;         // [128][72]
    unsigned short* sP  = sm + 26624;         // [4 waves][16][72]
    int tid = threadIdx.x;
    int wy = tid >> 6, lane = tid & 63, ln = lane & 15, quad = lane >> 4;
    int qtx = blockIdx.x, be = blockIdx.y;
    int qt = (be & 16) ? (15 - qtx) : qtx;
    int q0w = qt * 64 + wy * 16;
    s16x8 qh[4], qlo[4];
    {
        const unsigned short* qrh = Qh + ((size_t)be * KSEL + q0w + ln) * HPD + quad * 8;
        const unsigned short* qrl = Ql + ((size_t)be * KSEL + q0w + ln) * HPD + quad * 8;
#pragma unroll
        for (int dc = 0; dc < 4; dc++) {
            qh[dc]  = *(const s16x8*)(qrh + dc * 32);
            qlo[dc] = *(const s16x8*)(qrl + dc * 32);
        }
    }
    f32x4 O[8];
#pragma unroll
    for (int f = 0; f < 8; f++) O[f] = (f32x4){0.f, 0.f, 0.f, 0.f};
    float m_[4] = {-INFINITY, -INFINITY, -INFINITY, -INFINITY};
    float l_[4] = {0.f, 0.f, 0.f, 0.f};
    const unsigned short* gKH = Kh + (size_t)be * KSEL * HPD;
    const unsigned short* gKL = Kl + (size_t)be * KSEL * HPD;
    const unsigned short* gVT = Vt + (size_t)be * HPD * KSEL;
    unsigned short* Pw = sP + wy * 1152;
    for (int kt = 0; kt <= qt; kt++) {
        __syncthreads();
        for (int j = tid; j < 1024; j += 256) {
            int row = j >> 4, seg = j & 15;
            size_t g = (size_t)(kt * 64 + row) * HPD + seg * 8;
            *(uint4*)(sKH + row * 136 + seg * 8) = *(const uint4*)(gKH + g);
            *(uint4*)(sKL + row * 136 + seg * 8) = *(const uint4*)(gKL + g);
        }
        for (int j = tid; j < 1024; j += 256) {
            int row = j >> 3, seg = j & 7;
            *(uint4*)(sVT + row * 72 + seg * 8) =
                *(const uint4*)(gVT + (size_t)row * KSEL + kt * 64 + seg * 8);
        }
        __syncthreads();
        f32x4 s4[4];
#pragma unroll
        for (int f = 0; f < 4; f++) s4[f] = (f32x4){0.f, 0.f, 0.f, 0.f};
#pragma unroll
        for (int dc = 0; dc < 4; dc++) {
#pragma unroll
            for (int f = 0; f < 4; f++) {
                s16x8 kh = *(const s16x8*)(sKH + (f * 16 + ln) * 136 + dc * 32 + quad * 8);
                s16x8 kl = *(const s16x8*)(sKL + (f * 16 + ln) * 136 + dc * 32 + quad * 8);
                s4[f] = mfma16(qh[dc], kh, s4[f]);
                s4[f] = mfma16(qlo[dc], kh, s4[f]);
                s4[f] = mfma16(qh[dc], kl, s4[f]);
            }
        }
        if (kt == qt) {
            int qloc = wy * 16 + quad * 4;
#pragma unroll
            for (int f = 0; f < 4; f++)
#pragma unroll
                for (int r = 0; r < 4; r++)
                    if (f * 16 + ln > qloc + r) s4[f][r] = -INFINITY;
        }
        float alpha[4];
#pragma unroll
        for (int r = 0; r < 4; r++) {
            float mr = fmaxf(fmaxf(s4[0][r], s4[1][r]), fmaxf(s4[2][r], s4[3][r]));
            mr = fmaxf(mr, __shfl_xor(mr, 1, 64));
            mr = fmaxf(mr, __shfl_xor(mr, 2, 64));
            mr = fmaxf(mr, __shfl_xor(mr, 4, 64));
            mr = fmaxf(mr, __shfl_xor(mr, 8, 64));
            float mn = fmaxf(m_[r], mr);
            alpha[r] = __expf(m_[r] - mn);
            float rs = 0.f;
#pragma unroll
            for (int f = 0; f < 4; f++) {
                float p = __expf(s4[f][r] - mn);
                s4[f][r] = p; rs += p;
            }
            rs += __shfl_xor(rs, 1, 64);
            rs += __shfl_xor(rs, 2, 64);
            rs += __shfl_xor(rs, 4, 64);
            rs += __shfl_xor(rs, 8, 64);
            l_[r] = l_[r] * alpha[r] + rs;
            m_[r] = mn;
        }
#pragma unroll
        for (int f = 0; f < 4; f++)
#pragma unroll
            for (int r = 0; r < 4; r++)
                Pw[(quad * 4 + r) * 72 + f * 16 + ln] = f2bf(s4[f][r]);
#pragma unroll
        for (int f = 0; f < 8; f++) {
            O[f][0] *= alpha[0]; O[f][1] *= alpha[1];
            O[f][2] *= alpha[2]; O[f][3] *= alpha[3];
        }
        s16x8 p0 = *(const s16x8*)(Pw + ln * 72 + quad * 8);
        s16x8 p1 = *(const s16x8*)(Pw + ln * 72 + 32 + quad * 8);
#pragma unroll
        for (int f = 0; f < 8; f++) {
            s16x8 v0 = *(const s16x8*)(sVT + (f * 16 + ln) * 72 + quad * 8);
            s16x8 v1 = *(const s16x8*)(sVT + (f * 16 + ln) * 72 + 32 + quad * 8);
            O[f] = mfma16(p0, v0, O[f]);
            O[f] = mfma16(p1, v1, O[f]);
        }
    }
#pragma unroll
    for (int r = 0; r < 4; r++) {
        int row = q0w + quad * 4 + r;
        float gs = gate[be * KSEL + row] / l_[r];
        size_t base = ((size_t)be * KSEL + row) * HPD + ln;
#pragma unroll
        for (int f = 0; f < 8; f++) {
            float v = O[f][r] * gs;
            unsigned short h = f2bf(v);
            AVh[base + f * 16] = h;
            AVl[base + f * 16] = f2bf(v - bf2f(h));
        }
    }
}

// ---------------- 5. out projection: MFMA bf16 3-pass, single launch, atomic scatter ----
// LDS 74 KB -> 2 blocks/CU = 2 waves/EU at 256 threads; pin so acc[4][4] (64 regs) fits.
__global__ __launch_bounds__(256)
__attribute__((amdgpu_waves_per_eu(2, 2)))
void proj_kernel(const unsigned short* __restrict__ AVh,
                 const unsigned short* __restrict__ AVl,
                 const unsigned short* __restrict__ Woh,
                 const unsigned short* __restrict__ Wol,
                 const int* __restrict__ topk_idx,
                 float* __restrict__ out) {
    __shared__ __align__(16) unsigned short smem[4 * 128 * LDA];   // 73728 B
    __shared__ int rows_s[128];
    unsigned short* Ah = smem;
    unsigned short* Al = smem + 128 * LDA;
    unsigned short* Bh = smem + 2 * 128 * LDA;
    unsigned short* Bl = smem + 3 * 128 * LDA;
    int tid = threadIdx.x;
    int w = tid >> 6, lane = tid & 63, ln = lane & 15, quad = lane >> 4;
    int wm = w >> 1, wn = w & 1;
    int mt = blockIdx.x, nt = blockIdx.y, be = blockIdx.z;
    int b = be >> 3, e = be & 7;
    if (tid < 128) rows_s[tid] = topk_idx[be * KSEL + mt * 128 + tid];
    __syncthreads();

    f32x4 acc[4][4];
#pragma unroll
    for (int mf = 0; mf < 4; mf++)
#pragma unroll
        for (int nf = 0; nf < 4; nf++) acc[mf][nf] = (f32x4){0.f, 0.f, 0.f, 0.f};

    int ar = tid >> 1, ahf = tid & 1;
    const unsigned short* ash = AVh + ((size_t)be * KSEL + mt * 128 + ar) * HPD + ahf * 32;
    const unsigned short* asl = AVl + ((size_t)be * KSEL + mt * 128 + ar) * HPD + ahf * 32;
    const unsigned short* wbh = Woh + ((size_t)e * HH + nt * 128) * HPD;
    const unsigned short* wbl = Wol + ((size_t)e * HH + nt * 128) * HPD;
    int brow = tid >> 3, bseg = tid & 7;

    for (int k0 = 0; k0 < HPD; k0 += 64) {
        // A copy (already bf16 hi/lo)
#pragma unroll
        for (int i = 0; i < 4; i++) {
            *(uint4*)(Ah + ar * LDA + ahf * 32 + i * 8) = *(const uint4*)(ash + k0 + i * 8);
            *(uint4*)(Al + ar * LDA + ahf * 32 + i * 8) = *(const uint4*)(asl + k0 + i * 8);
        }
#pragma unroll
        for (int s = 0; s < 8; s++) {
            const unsigned short* sp = ((s < 4) ? wbh : wbl) +
                (size_t)((s & 3) * 32 + brow) * HPD + k0 + bseg * 8;
            unsigned short* dst = ((s < 4) ? Bh : Bl) + ((s & 3) * 32 + brow) * LDA + bseg * 8;
            *(uint4*)dst = *(const uint4*)sp;
        }
        __syncthreads();
#pragma unroll
        for (int kk = 0; kk < 2; kk++) {
            s16x8 a_h[4], a_l[4];
#pragma unroll
            for (int mf = 0; mf < 4; mf++) {
                const unsigned short* p = Ah + (wm * 64 + mf * 16 + ln) * LDA + kk * 32 + quad * 8;
                a_h[mf] = *(const s16x8*)p;
                a_l[mf] = *(const s16x8*)(p + 128 * LDA);
            }
#pragma unroll
            for (int nf = 0; nf < 4; nf++) {
                const unsigned short* p = Bh + (wn * 64 + nf * 16 + ln) * LDA + kk * 32 + quad * 8;
                s16x8 b_h = *(const s16x8*)p;
                s16x8 b_l = *(const s16x8*)(p + 128 * LDA);
#pragma unroll
                for (int mf = 0; mf < 4; mf++) {
                    acc[mf][nf] = mfma16(a_h[mf], b_h, acc[mf][nf]);
                    acc[mf][nf] = mfma16(a_l[mf], b_h, acc[mf][nf]);
                    acc[mf][nf] = mfma16(a_h[mf], b_l, acc[mf][nf]);
                }
            }
        }
        __syncthreads();
    }
#pragma unroll
    for (int mf = 0; mf < 4; mf++)
#pragma unroll
        for (int r = 0; r < 4; r++) {
            int pos = rows_s[wm * 64 + mf * 16 + quad * 4 + r];
            float* ob = out + ((size_t)b * TT + pos) * HH + nt * 128;
#pragma unroll
            for (int nf = 0; nf < 4; nf++)
                atomicAdd(ob + wn * 64 + nf * 16 + ln, acc[mf][nf][r]);
        }
}

extern "C" void kernel_launch(void* const* d_in, const int* in_sizes, int n_in,
                              void* d_out, int out_size, void* d_ws, size_t ws_size,
                              hipStream_t stream) {
    const float* X    = (const float*)d_in[0];
    const float* Wr   = (const float*)d_in[1];
    const float* Wqkv = (const float*)d_in[2];
    const float* Wo   = (const float*)d_in[3];
    float* out = (float*)d_out;
    char* ws = (char*)d_ws;
    float* L    = (float*)(ws + OFF_L);
    int*   idx  = (int*)(ws + OFF_IDX);
    float* gate = (float*)(ws + OFF_GATE);
    float2* trig = (float2*)(ws + OFF_TRIG);
    unsigned short* Qh = (unsigned short*)(ws + OFF_QH);
    unsigned short* Ql = (unsigned short*)(ws + OFF_QL);
    unsigned short* Kh = (unsigned short*)(ws + OFF_KH);
    unsigned short* Kl = (unsigned short*)(ws + OFF_KL);
    unsigned short* Vt = (unsigned short*)(ws + OFF_VT);
    unsigned short* AVh = (unsigned short*)(ws + OFF_AVH);
    unsigned short* AVl = (unsigned short*)(ws + OFF_AVL);
    unsigned short* Wth = (unsigned short*)(ws + OFF_WTH);
    unsigned short* Wtl = (unsigned short*)(ws + OFF_WTL);
    unsigned short* Woh = (unsigned short*)(ws + OFF_WOH);
    unsigned short* Wol = (unsigned short*)(ws + OFF_WOL);

    hipMemsetAsync(d_out, 0, (size_t)BB * TT * HH * sizeof(float), stream);
    trig_kernel<<<TT * 32 / 256, 256, 0, stream>>>(trig);
    wprep_kernel<<<dim3(HH / 32, QW / 32, EE), 256, 0, stream>>>(Wqkv, Wth, Wtl);
    wo_prep_kernel<<<dim3(HPD / 32, HH / 32, EE), 256, 0, stream>>>(Wo, Woh, Wol);
    router_kernel<<<BB * TT / 4, 256, 0, stream>>>(X, Wr, L);
    topk_kernel<<<BB * EE, 1024, 0, stream>>>(L, idx, gate);
    qkv_kernel<<<dim3(KSEL / 128, 3, BB * EE), 512, 0, stream>>>(X, Wth, Wtl, idx, trig,
                                                                 Qh, Ql, Kh, Kl, Vt);
    attn_kernel<<<dim3(16, BB * EE), 256, 0, stream>>>(Qh, Ql, Kh, Kl, Vt, gate, AVh, AVl);
    proj_kernel<<<dim3(KSEL / 128, HH / 128, BB * EE), 256, 0, stream>>>(AVh, AVl, Woh, Wol,
                                                                         idx, out);
}

// Round 9
// 621.903 us; speedup vs baseline: 1.1115x; 1.1115x over previous
//
#include <hip/hip_runtime.h>
#include <math.h>

#define BB 4
#define TT 8192
#define EE 8
#define HH 1024
#define HPD 128
#define KSEL 1024
#define QW 384   // 3*HP

typedef __attribute__((ext_vector_type(8))) short s16x8;
typedef __attribute__((ext_vector_type(4))) float f32x4;

// ---- workspace layout (bytes) ----
#define OFF_L    ((size_t)0)                                   // float[B*T*E]          1 MB
#define OFF_IDX  (OFF_L    + (size_t)BB*TT*EE*4)               // int[B*E*K]            128 KB
#define OFF_GATE (OFF_IDX  + (size_t)BB*EE*KSEL*4)             // float[B*E*K]          128 KB
#define OFF_TRIG (OFF_GATE + (size_t)BB*EE*KSEL*4)             // float2[8192*32]       2 MB
#define OFF_QH   (OFF_TRIG + (size_t)TT*32*8)                  // bf16[B*E*K*128]       8 MB
#define OFF_QL   (OFF_QH   + (size_t)BB*EE*KSEL*HPD*2)
#define OFF_KH   (OFF_QL   + (size_t)BB*EE*KSEL*HPD*2)
#define OFF_KL   (OFF_KH   + (size_t)BB*EE*KSEL*HPD*2)
#define OFF_VT   (OFF_KL   + (size_t)BB*EE*KSEL*HPD*2)         // bf16[B*E*128*K] transposed
#define OFF_AVH  (OFF_VT   + (size_t)BB*EE*KSEL*HPD*2)         // bf16[B*E*K*128]       8 MB
#define OFF_AVL  (OFF_AVH  + (size_t)BB*EE*KSEL*HPD*2)         // bf16[B*E*K*128]       8 MB
#define OFF_WTH  (OFF_AVL  + (size_t)BB*EE*KSEL*HPD*2)         // bf16[E][384][1024]    6.3 MB
#define OFF_WTL  (OFF_WTH  + (size_t)EE*QW*HH*2)
#define OFF_WOH  (OFF_WTL  + (size_t)EE*QW*HH*2)               // bf16[E][1024][128]    2 MB
#define OFF_WOL  (OFF_WOH  + (size_t)EE*HH*HPD*2)

static __device__ inline unsigned short f2bf(float x) {        // fp32 -> bf16 bits, RNE
    unsigned u = __float_as_uint(x);
    return (unsigned short)((u + 0x7fffu + ((u >> 16) & 1u)) >> 16);
}
static __device__ inline float bf2f(unsigned short h) {
    return __uint_as_float((unsigned)h << 16);
}
static __device__ inline unsigned cvtpk(float lo, float hi) {  // packed 2xf32 -> 2xbf16
    unsigned r;
    asm("v_cvt_pk_bf16_f32 %0, %1, %2" : "=v"(r) : "v"(lo), "v"(hi));
    return r;
}
static __device__ inline f32x4 mfma16(s16x8 a, s16x8 b, f32x4 c) {
    return __builtin_amdgcn_mfma_f32_16x16x32_bf16(a, b, c, 0, 0, 0);
}

// ---------------- 0. trig table ----------------
__global__ __launch_bounds__(256) void trig_kernel(float2* __restrict__ trig) {
    int i = blockIdx.x * 256 + threadIdx.x;      // i < 8192*32
    int pos = i >> 5, j = i & 31;
    double inv = pow(10000.0, -(double)(2 * j) / 64.0);
    double a = (double)pos * inv;
    trig[i] = make_float2((float)cos(a), (float)sin(a));
}

// ---------------- 0b. Wqkv prep: [e][k][n] -> [e][n][k], bf16 hi/lo ----------------
__global__ __launch_bounds__(256) void wprep_kernel(const float* __restrict__ Wqkv,
                                                    unsigned short* __restrict__ Wth,
                                                    unsigned short* __restrict__ Wtl) {
    __shared__ float t[32][33];
    int kt = blockIdx.x, nt = blockIdx.y, e = blockIdx.z;
    int lx = threadIdx.x & 31, ly = threadIdx.x >> 5;         // 32 x 8
    const float* src = Wqkv + (size_t)e * HH * QW;
#pragma unroll
    for (int i = 0; i < 4; i++) {
        int yy = ly + i * 8;
        t[yy][lx] = src[(size_t)(kt * 32 + yy) * QW + nt * 32 + lx];
    }
    __syncthreads();
#pragma unroll
    for (int i = 0; i < 4; i++) {
        int yy = ly + i * 8;                                   // n within tile
        float v = t[lx][yy];
        unsigned short h = f2bf(v);
        unsigned short l = f2bf(v - bf2f(h));
        size_t o = ((size_t)e * QW + nt * 32 + yy) * HH + kt * 32 + lx;
        Wth[o] = h;
        Wtl[o] = l;
    }
}

// ---------------- 0c. Wo prep: [e][k=128][n=1024] -> [e][n][k], bf16 hi/lo ----------------
__global__ __launch_bounds__(256) void wo_prep_kernel(const float* __restrict__ Wo,
                                                      unsigned short* __restrict__ Woh,
                                                      unsigned short* __restrict__ Wol) {
    __shared__ float t[32][33];
    int kt = blockIdx.x, nt = blockIdx.y, e = blockIdx.z;     // kt<4, nt<32
    int lx = threadIdx.x & 31, ly = threadIdx.x >> 5;
    const float* src = Wo + (size_t)e * HPD * HH;
#pragma unroll
    for (int i = 0; i < 4; i++) {
        int yy = ly + i * 8;
        t[yy][lx] = src[(size_t)(kt * 32 + yy) * HH + nt * 32 + lx];
    }
    __syncthreads();
#pragma unroll
    for (int i = 0; i < 4; i++) {
        int yy = ly + i * 8;                                   // n within tile
        float v = t[lx][yy];
        unsigned short h = f2bf(v);
        unsigned short l = f2bf(v - bf2f(h));
        size_t o = ((size_t)e * HH + nt * 32 + yy) * HPD + kt * 32 + lx;
        Woh[o] = h;
        Wol[o] = l;
    }
}

// ---------------- 1. router ----------------
__global__ __launch_bounds__(256) void router_kernel(const float* __restrict__ X,
                                                     const float* __restrict__ Wr,
                                                     float* __restrict__ L) {
    __shared__ float wr_s[EE * HH];
    int tid = threadIdx.x;
    for (int i = tid; i < EE * HH; i += 256) wr_s[i] = Wr[i];
    __syncthreads();
    int wave = tid >> 6, lane = tid & 63;
    int row = blockIdx.x * 4 + wave;
    const float* xr = X + (size_t)row * HH;
    double acc[EE];
#pragma unroll
    for (int e = 0; e < EE; e++) acc[e] = 0.0;
#pragma unroll
    for (int it = 0; it < 4; it++) {
        int d0 = it * 256 + lane * 4;
        float4 x4 = *(const float4*)(xr + d0);
#pragma unroll
        for (int e = 0; e < EE; e++) {
            float4 w4 = *(const float4*)(wr_s + e * HH + d0);
            acc[e] += (double)x4.x * w4.x + (double)x4.y * w4.y +
                      (double)x4.z * w4.z + (double)x4.w * w4.w;
        }
    }
#pragma unroll
    for (int off = 32; off > 0; off >>= 1)
#pragma unroll
        for (int e = 0; e < EE; e++) acc[e] += __shfl_xor(acc[e], off, 64);
    if (lane < EE) L[(size_t)row * EE + lane] = (float)acc[lane];
}

// ---------------- 2. top-k (bitonic) then re-sort selected by index ASC ----------------
__global__ __launch_bounds__(1024) void topk_kernel(const float* __restrict__ L,
                                                    int* __restrict__ topk_idx,
                                                    float* __restrict__ gate) {
    __shared__ unsigned long long s[TT];          // 64 KB
    int be = blockIdx.x, b = be >> 3, e = be & 7;
    int tid = threadIdx.x;
    for (int t = tid; t < TT; t += 1024) {
        float v = L[((size_t)b * TT + t) * EE + e];
        unsigned u = __float_as_uint(v);
        u ^= (u >> 31) ? 0xFFFFFFFFu : 0x80000000u;
        unsigned inv = ~u;
        s[t] = ((unsigned long long)inv << 32) | (unsigned)t;
    }
    __syncthreads();
    for (int size = 2; size <= TT; size <<= 1) {
        for (int stride = size >> 1; stride > 0; stride >>= 1) {
            for (int t = tid; t < TT / 2; t += 1024) {
                int j = t & (stride - 1);
                int lo = ((t ^ j) << 1) | j;
                int hi = lo + stride;
                unsigned long long a = s[lo], c = s[hi];
                bool asc = ((lo & size) == 0);
                if ((a > c) == asc) { s[lo] = c; s[hi] = a; }
            }
            __syncthreads();
        }
    }
    unsigned long long key = 0;
    if (tid < KSEL) {
        int idx = (int)(unsigned)s[tid];
        float v = L[((size_t)b * TT + idx) * EE + e];
        float g = 1.0f / (1.0f + expf(-v));
        key = ((unsigned long long)(unsigned)idx << 32) | __float_as_uint(g);
    }
    __syncthreads();
    if (tid < KSEL) s[tid] = key;
    __syncthreads();
    for (int size = 2; size <= KSEL; size <<= 1) {
        for (int stride = size >> 1; stride > 0; stride >>= 1) {
            int t = tid;
            if (t < KSEL / 2) {
                int j = t & (stride - 1);
                int lo = ((t ^ j) << 1) | j;
                int hi = lo + stride;
                unsigned long long a = s[lo], c = s[hi];
                bool asc = ((lo & size) == 0);
                if ((a > c) == asc) { s[lo] = c; s[hi] = a; }
            }
            __syncthreads();
        }
    }
    if (tid < KSEL) {
        topk_idx[be * KSEL + tid] = (int)(s[tid] >> 32);
        gate[be * KSEL + tid] = __uint_as_float((unsigned)s[tid]);
    }
}

// ---------------- 3. QKV GEMM via MFMA bf16 hi/lo 3-pass + fused RoPE ----------------
// 128x128 tile, BK=64, 512 threads = 8 waves (4 row x 2 col), each wave 32x64.
// TRANSIENT staging: nothing live across the barrier except acc (32) + pointers.
// (The r2-r7 spill source was cross-barrier prefetch regs the allocator won't fund;
//  global_load_lds is banned: 3/3 container kills. Inter-block TLP covers overlap.)
#define LDA 72   // 144 B rows = 9 x 16 B
__global__ __launch_bounds__(512) void qkv_kernel(const float* __restrict__ X,
                                                  const unsigned short* __restrict__ Wth,
                                                  const unsigned short* __restrict__ Wtl,
                                                  const int* __restrict__ topk_idx,
                                                  const float2* __restrict__ trig,
                                                  unsigned short* __restrict__ Qh,
                                                  unsigned short* __restrict__ Ql,
                                                  unsigned short* __restrict__ Kh,
                                                  unsigned short* __restrict__ Kl,
                                                  unsigned short* __restrict__ Vt) {
    __shared__ __align__(16) unsigned short smem[4 * 128 * LDA];   // 73728 B
    __shared__ int rows_s[128];
    unsigned short* Ah = smem;                  // [128][72]
    unsigned short* Al = smem + 128 * LDA;
    unsigned short* Bh = smem + 2 * 128 * LDA;  // [128 n][72 k]
    unsigned short* Bl = smem + 3 * 128 * LDA;
    int tid = threadIdx.x;
    int w = tid >> 6, lane = tid & 63, ln = lane & 15, quad = lane >> 4;
    int wm = w >> 1, wn = w & 1;                // wm<4 (32-row strips), wn<2 (64-col strips)
    int mt = blockIdx.x, nt = blockIdx.y, be = blockIdx.z;
    int b = be >> 3, e = be & 7;
    if (tid < 128) rows_s[tid] = topk_idx[be * KSEL + mt * 128 + tid];
    __syncthreads();

    f32x4 acc[2][4];
#pragma unroll
    for (int mf = 0; mf < 2; mf++)
#pragma unroll
        for (int nf = 0; nf < 4; nf++) acc[mf][nf] = (f32x4){0.f, 0.f, 0.f, 0.f};

    const float* xb = X + (size_t)b * TT * HH;
    const unsigned short* wbh = Wth + ((size_t)e * QW + nt * 128) * HH;
    const unsigned short* wbl = Wtl + ((size_t)e * QW + nt * 128) * HH;
    int ar = tid >> 2, aq = tid & 3;                  // A: row, 16-col quarter
    const float* asrc = xb + (size_t)rows_s[ar] * HH + aq * 16;

    for (int k0 = 0; k0 < HH; k0 += 64) {
        // (a) B: transient copy global -> LDS (4 x 16B chunks/thread, loads batch early)
#pragma unroll
        for (int s = 0; s < 4; s++) {
            int c = s * 512 + tid;                    // 16B-chunk id in [0,2048)
            int buf = c >> 10, idx = c & 1023;
            int row = idx >> 3, seg = idx & 7;
            const unsigned short* sp = (buf ? wbl : wbh) + (size_t)row * HH + k0 + seg * 8;
            unsigned short* dst = (buf ? Bl : Bh) + row * LDA + seg * 8;
            *(uint4*)dst = *(const uint4*)sp;
        }
        // (b) A: transient load 16 fp32 -> hi/lo bf16 -> LDS
        {
            const float* src = asrc + k0;
            unsigned short* dh = Ah + ar * LDA + aq * 16;
            unsigned short* dl = Al + ar * LDA + aq * 16;
#pragma unroll
            for (int i = 0; i < 2; i++) {
                float4 x = *(const float4*)(src + i * 8);
                float4 y = *(const float4*)(src + i * 8 + 4);
                unsigned h0 = cvtpk(x.x, x.y), h1 = cvtpk(x.z, x.w);
                unsigned h2 = cvtpk(y.x, y.y), h3 = cvtpk(y.z, y.w);
                float l0 = x.x - __uint_as_float(h0 << 16);
                float l1 = x.y - __uint_as_float(h0 & 0xffff0000u);
                float l2 = x.z - __uint_as_float(h1 << 16);
                float l3 = x.w - __uint_as_float(h1 & 0xffff0000u);
                float l4 = y.x - __uint_as_float(h2 << 16);
                float l5 = y.y - __uint_as_float(h2 & 0xffff0000u);
                float l6 = y.z - __uint_as_float(h3 << 16);
                float l7 = y.w - __uint_as_float(h3 & 0xffff0000u);
                *(uint4*)(dh + i * 8) = make_uint4(h0, h1, h2, h3);
                *(uint4*)(dl + i * 8) = make_uint4(cvtpk(l0, l1), cvtpk(l2, l3),
                                                   cvtpk(l4, l5), cvtpk(l6, l7));
            }
        }
        __syncthreads();
#pragma unroll
        for (int kk = 0; kk < 2; kk++) {
            s16x8 a_h[2], a_l[2];
#pragma unroll
            for (int mf = 0; mf < 2; mf++) {
                const unsigned short* p = Ah + (wm * 32 + mf * 16 + ln) * LDA + kk * 32 + quad * 8;
                a_h[mf] = *(const s16x8*)p;
                a_l[mf] = *(const s16x8*)(p + 128 * LDA);
            }
#pragma unroll
            for (int nf = 0; nf < 4; nf++) {
                const unsigned short* p = Bh + (wn * 64 + nf * 16 + ln) * LDA + kk * 32 + quad * 8;
                s16x8 b_h = *(const s16x8*)p;
                s16x8 b_l = *(const s16x8*)(p + 128 * LDA);
#pragma unroll
                for (int mf = 0; mf < 2; mf++) {
                    acc[mf][nf] = mfma16(a_h[mf], b_h, acc[mf][nf]);
                    acc[mf][nf] = mfma16(a_l[mf], b_h, acc[mf][nf]);
                    acc[mf][nf] = mfma16(a_h[mf], b_l, acc[mf][nf]);
                }
            }
        }
        __syncthreads();
    }

    if (nt < 2) {
        // RoPE: cols 0..63 live in wn==0 waves; pair (j, j+32) = frags (nf, nf+2), lane-local
        if (wn == 0) {
#pragma unroll
            for (int mf = 0; mf < 2; mf++)
#pragma unroll
                for (int r = 0; r < 4; r++) {
                    int pos = rows_s[wm * 32 + mf * 16 + quad * 4 + r];
#pragma unroll
                    for (int nf = 0; nf < 2; nf++) {
                        int j = nf * 16 + ln;
                        float2 sc = trig[pos * 32 + j];
                        float own = acc[mf][nf][r], oth = acc[mf][nf + 2][r];
                        acc[mf][nf][r]     = own * sc.x - oth * sc.y;
                        acc[mf][nf + 2][r] = oth * sc.x + own * sc.y;
                    }
                }
        }
        float qs = (nt == 0) ? 0.08838834764831845f : 1.0f;
        unsigned short* Ph = (nt == 0) ? Qh : Kh;
        unsigned short* Pl = (nt == 0) ? Ql : Kl;
#pragma unroll
        for (int mf = 0; mf < 2; mf++)
#pragma unroll
            for (int r = 0; r < 4; r++) {
                int rowg = mt * 128 + wm * 32 + mf * 16 + quad * 4 + r;
                size_t rb = ((size_t)be * KSEL + rowg) * HPD;
#pragma unroll
                for (int nf = 0; nf < 4; nf++) {
                    int col = wn * 64 + nf * 16 + ln;
                    float x = acc[mf][nf][r] * qs;
                    unsigned short h = f2bf(x);
                    Ph[rb + col] = h;
                    Pl[rb + col] = f2bf(x - bf2f(h));
                }
            }
    } else {
        // V: transpose 128x128 through LDS (reuse staging region), write Vt coalesced
        unsigned short* T = smem;                 // [128 d][136 m]
#pragma unroll
        for (int mf = 0; mf < 2; mf++)
#pragma unroll
            for (int nf = 0; nf < 4; nf++)
#pragma unroll
                for (int r = 0; r < 4; r++)
                    T[(wn * 64 + nf * 16 + ln) * 136 + wm * 32 + mf * 16 + quad * 4 + r] =
                        f2bf(acc[mf][nf][r]);
        __syncthreads();
        for (int j = tid; j < 2048; j += 512) {
            int d = j >> 4, mseg = j & 15;
            uint4 v = *(uint4*)&T[d * 136 + mseg * 8];
            *(uint4*)(Vt + ((size_t)be * HPD + d) * KSEL + mt * 128 + mseg * 8) = v;
        }
    }
}

// ---------------- 4. causal flash attention, MFMA 16x16x32 bf16 ----------------
__global__ __launch_bounds__(256)
__attribute__((amdgpu_waves_per_eu(2, 2)))
void attn_kernel(const unsigned short* __restrict__ Qh,
                 const unsigned short* __restrict__ Ql,
                 const unsigned short* __restrict__ Kh,
                 const unsigned short* __restrict__ Kl,
                 const unsigned short* __restrict__ Vt,
                 const float* __restrict__ gate,
                 unsigned short* __restrict__ AVh,
                 unsigned short* __restrict__ AVl) {
    __shared__ __align__(16) unsigned short sm[31232];  // 62464 B
    unsigned short* sKH = sm;                 // [64][136]
    unsigned short* sKL = sm + 8704;          // [64][136]
    unsigned short* sVT = sm + 17408;         // [128][72]
    unsigned short* sP  = sm + 26624;         // [4 waves][16][72]
    int tid = threadIdx.x;
    int wy = tid >> 6, lane = tid & 63, ln = lane & 15, quad = lane >> 4;
    int qtx = blockIdx.x, be = blockIdx.y;
    int qt = (be & 16) ? (15 - qtx) : qtx;
    int q0w = qt * 64 + wy * 16;
    s16x8 qh[4], qlo[4];
    {
        const unsigned short* qrh = Qh + ((size_t)be * KSEL + q0w + ln) * HPD + quad * 8;
        const unsigned short* qrl = Ql + ((size_t)be * KSEL + q0w + ln) * HPD + quad * 8;
#pragma unroll
        for (int dc = 0; dc < 4; dc++) {
            qh[dc]  = *(const s16x8*)(qrh + dc * 32);
            qlo[dc] = *(const s16x8*)(qrl + dc * 32);
        }
    }
    f32x4 O[8];
#pragma unroll
    for (int f = 0; f < 8; f++) O[f] = (f32x4){0.f, 0.f, 0.f, 0.f};
    float m_[4] = {-INFINITY, -INFINITY, -INFINITY, -INFINITY};
    float l_[4] = {0.f, 0.f, 0.f, 0.f};
    const unsigned short* gKH = Kh + (size_t)be * KSEL * HPD;
    const unsigned short* gKL = Kl + (size_t)be * KSEL * HPD;
    const unsigned short* gVT = Vt + (size_t)be * HPD * KSEL;
    unsigned short* Pw = sP + wy * 1152;
    for (int kt = 0; kt <= qt; kt++) {
        __syncthreads();
        for (int j = tid; j < 1024; j += 256) {
            int row = j >> 4, seg = j & 15;
            size_t g = (size_t)(kt * 64 + row) * HPD + seg * 8;
            *(uint4*)(sKH + row * 136 + seg * 8) = *(const uint4*)(gKH + g);
            *(uint4*)(sKL + row * 136 + seg * 8) = *(const uint4*)(gKL + g);
        }
        for (int j = tid; j < 1024; j += 256) {
            int row = j >> 3, seg = j & 7;
            *(uint4*)(sVT + row * 72 + seg * 8) =
                *(const uint4*)(gVT + (size_t)row * KSEL + kt * 64 + seg * 8);
        }
        __syncthreads();
        f32x4 s4[4];
#pragma unroll
        for (int f = 0; f < 4; f++) s4[f] = (f32x4){0.f, 0.f, 0.f, 0.f};
#pragma unroll
        for (int dc = 0; dc < 4; dc++) {
#pragma unroll
            for (int f = 0; f < 4; f++) {
                s16x8 kh = *(const s16x8*)(sKH + (f * 16 + ln) * 136 + dc * 32 + quad * 8);
                s16x8 kl = *(const s16x8*)(sKL + (f * 16 + ln) * 136 + dc * 32 + quad * 8);
                s4[f] = mfma16(qh[dc], kh, s4[f]);
                s4[f] = mfma16(qlo[dc], kh, s4[f]);
                s4[f] = mfma16(qh[dc], kl, s4[f]);
            }
        }
        if (kt == qt) {
            int qloc = wy * 16 + quad * 4;
#pragma unroll
            for (int f = 0; f < 4; f++)
#pragma unroll
                for (int r = 0; r < 4; r++)
                    if (f * 16 + ln > qloc + r) s4[f][r] = -INFINITY;
        }
        float alpha[4];
#pragma unroll
        for (int r = 0; r < 4; r++) {
            float mr = fmaxf(fmaxf(s4[0][r], s4[1][r]), fmaxf(s4[2][r], s4[3][r]));
            mr = fmaxf(mr, __shfl_xor(mr, 1, 64));
            mr = fmaxf(mr, __shfl_xor(mr, 2, 64));
            mr = fmaxf(mr, __shfl_xor(mr, 4, 64));
            mr = fmaxf(mr, __shfl_xor(mr, 8, 64));
            float mn = fmaxf(m_[r], mr);
            alpha[r] = __expf(m_[r] - mn);
            float rs = 0.f;
#pragma unroll
            for (int f = 0; f < 4; f++) {
                float p = __expf(s4[f][r] - mn);
                s4[f][r] = p; rs += p;
            }
            rs += __shfl_xor(rs, 1, 64);
            rs += __shfl_xor(rs, 2, 64);
            rs += __shfl_xor(rs, 4, 64);
            rs += __shfl_xor(rs, 8, 64);
            l_[r] = l_[r] * alpha[r] + rs;
            m_[r] = mn;
        }
#pragma unroll
        for (int f = 0; f < 4; f++)
#pragma unroll
            for (int r = 0; r < 4; r++)
                Pw[(quad * 4 + r) * 72 + f * 16 + ln] = f2bf(s4[f][r]);
#pragma unroll
        for (int f = 0; f < 8; f++) {
            O[f][0] *= alpha[0]; O[f][1] *= alpha[1];
            O[f][2] *= alpha[2]; O[f][3] *= alpha[3];
        }
        s16x8 p0 = *(const s16x8*)(Pw + ln * 72 + quad * 8);
        s16x8 p1 = *(const s16x8*)(Pw + ln * 72 + 32 + quad * 8);
#pragma unroll
        for (int f = 0; f < 8; f++) {
            s16x8 v0 = *(const s16x8*)(sVT + (f * 16 + ln) * 72 + quad * 8);
            s16x8 v1 = *(const s16x8*)(sVT + (f * 16 + ln) * 72 + 32 + quad * 8);
            O[f] = mfma16(p0, v0, O[f]);
            O[f] = mfma16(p1, v1, O[f]);
        }
    }
#pragma unroll
    for (int r = 0; r < 4; r++) {
        int row = q0w + quad * 4 + r;
        float gs = gate[be * KSEL + row] / l_[r];
        size_t base = ((size_t)be * KSEL + row) * HPD + ln;
#pragma unroll
        for (int f = 0; f < 8; f++) {
            float v = O[f][r] * gs;
            unsigned short h = f2bf(v);
            AVh[base + f * 16] = h;
            AVl[base + f * 16] = f2bf(v - bf2f(h));
        }
    }
}

// ---------------- 5. out projection: MFMA bf16 3-pass, single launch, atomic scatter ----
__global__ __launch_bounds__(256)
__attribute__((amdgpu_waves_per_eu(2, 2)))
void proj_kernel(const unsigned short* __restrict__ AVh,
                 const unsigned short* __restrict__ AVl,
                 const unsigned short* __restrict__ Woh,
                 const unsigned short* __restrict__ Wol,
                 const int* __restrict__ topk_idx,
                 float* __restrict__ out) {
    __shared__ __align__(16) unsigned short smem[4 * 128 * LDA];   // 73728 B
    __shared__ int rows_s[128];
    unsigned short* Ah = smem;
    unsigned short* Al = smem + 128 * LDA;
    unsigned short* Bh = smem + 2 * 128 * LDA;
    unsigned short* Bl = smem + 3 * 128 * LDA;
    int tid = threadIdx.x;
    int w = tid >> 6, lane = tid & 63, ln = lane & 15, quad = lane >> 4;
    int wm = w >> 1, wn = w & 1;
    int mt = blockIdx.x, nt = blockIdx.y, be = blockIdx.z;
    int b = be >> 3, e = be & 7;
    if (tid < 128) rows_s[tid] = topk_idx[be * KSEL + mt * 128 + tid];
    __syncthreads();

    f32x4 acc[4][4];
#pragma unroll
    for (int mf = 0; mf < 4; mf++)
#pragma unroll
        for (int nf = 0; nf < 4; nf++) acc[mf][nf] = (f32x4){0.f, 0.f, 0.f, 0.f};

    int ar = tid >> 1, ahf = tid & 1;
    const unsigned short* ash = AVh + ((size_t)be * KSEL + mt * 128 + ar) * HPD + ahf * 32;
    const unsigned short* asl = AVl + ((size_t)be * KSEL + mt * 128 + ar) * HPD + ahf * 32;
    const unsigned short* wbh = Woh + ((size_t)e * HH + nt * 128) * HPD;
    const unsigned short* wbl = Wol + ((size_t)e * HH + nt * 128) * HPD;
    int brow = tid >> 3, bseg = tid & 7;

    for (int k0 = 0; k0 < HPD; k0 += 64) {
        // A copy (already bf16 hi/lo)
#pragma unroll
        for (int i = 0; i < 4; i++) {
            *(uint4*)(Ah + ar * LDA + ahf * 32 + i * 8) = *(const uint4*)(ash + k0 + i * 8);
            *(uint4*)(Al + ar * LDA + ahf * 32 + i * 8) = *(const uint4*)(asl + k0 + i * 8);
        }
#pragma unroll
        for (int s = 0; s < 8; s++) {
            const unsigned short* sp = ((s < 4) ? wbh : wbl) +
                (size_t)((s & 3) * 32 + brow) * HPD + k0 + bseg * 8;
            unsigned short* dst = ((s < 4) ? Bh : Bl) + ((s & 3) * 32 + brow) * LDA + bseg * 8;
            *(uint4*)dst = *(const uint4*)sp;
        }
        __syncthreads();
#pragma unroll
        for (int kk = 0; kk < 2; kk++) {
            s16x8 a_h[4], a_l[4];
#pragma unroll
            for (int mf = 0; mf < 4; mf++) {
                const unsigned short* p = Ah + (wm * 64 + mf * 16 + ln) * LDA + kk * 32 + quad * 8;
                a_h[mf] = *(const s16x8*)p;
                a_l[mf] = *(const s16x8*)(p + 128 * LDA);
            }
#pragma unroll
            for (int nf = 0; nf < 4; nf++) {
                const unsigned short* p = Bh + (wn * 64 + nf * 16 + ln) * LDA + kk * 32 + quad * 8;
                s16x8 b_h = *(const s16x8*)p;
                s16x8 b_l = *(const s16x8*)(p + 128 * LDA);
#pragma unroll
                for (int mf = 0; mf < 4; mf++) {
                    acc[mf][nf] = mfma16(a_h[mf], b_h, acc[mf][nf]);
                    acc[mf][nf] = mfma16(a_l[mf], b_h, acc[mf][nf]);
                    acc[mf][nf] = mfma16(a_h[mf], b_l, acc[mf][nf]);
                }
            }
        }
        __syncthreads();
    }
#pragma unroll
    for (int mf = 0; mf < 4; mf++)
#pragma unroll
        for (int r = 0; r < 4; r++) {
            int pos = rows_s[wm * 64 + mf * 16 + quad * 4 + r];
            float* ob = out + ((size_t)b * TT + pos) * HH + nt * 128;
#pragma unroll
            for (int nf = 0; nf < 4; nf++)
                atomicAdd(ob + wn * 64 + nf * 16 + ln, acc[mf][nf][r]);
        }
}

extern "C" void kernel_launch(void* const* d_in, const int* in_sizes, int n_in,
                              void* d_out, int out_size, void* d_ws, size_t ws_size,
                              hipStream_t stream) {
    const float* X    = (const float*)d_in[0];
    const float* Wr   = (const float*)d_in[1];
    const float* Wqkv = (const float*)d_in[2];
    const float* Wo   = (const float*)d_in[3];
    float* out = (float*)d_out;
    char* ws = (char*)d_ws;
    float* L    = (float*)(ws + OFF_L);
    int*   idx  = (int*)(ws + OFF_IDX);
    float* gate = (float*)(ws + OFF_GATE);
    float2* trig = (float2*)(ws + OFF_TRIG);
    unsigned short* Qh = (unsigned short*)(ws + OFF_QH);
    unsigned short* Ql = (unsigned short*)(ws + OFF_QL);
    unsigned short* Kh = (unsigned short*)(ws + OFF_KH);
    unsigned short* Kl = (unsigned short*)(ws + OFF_KL);
    unsigned short* Vt = (unsigned short*)(ws + OFF_VT);
    unsigned short* AVh = (unsigned short*)(ws + OFF_AVH);
    unsigned short* AVl = (unsigned short*)(ws + OFF_AVL);
    unsigned short* Wth = (unsigned short*)(ws + OFF_WTH);
    unsigned short* Wtl = (unsigned short*)(ws + OFF_WTL);
    unsigned short* Woh = (unsigned short*)(ws + OFF_WOH);
    unsigned short* Wol = (unsigned short*)(ws + OFF_WOL);

    hipMemsetAsync(d_out, 0, (size_t)BB * TT * HH * sizeof(float), stream);
    trig_kernel<<<TT * 32 / 256, 256, 0, stream>>>(trig);
    wprep_kernel<<<dim3(HH / 32, QW / 32, EE), 256, 0, stream>>>(Wqkv, Wth, Wtl);
    wo_prep_kernel<<<dim3(HPD / 32, HH / 32, EE), 256, 0, stream>>>(Wo, Woh, Wol);
    router_kernel<<<BB * TT / 4, 256, 0, stream>>>(X, Wr, L);
    topk_kernel<<<BB * EE, 1024, 0, stream>>>(L, idx, gate);
    qkv_kernel<<<dim3(KSEL / 128, 3, BB * EE), 512, 0, stream>>>(X, Wth, Wtl, idx, trig,
                                                                 Qh, Ql, Kh, Kl, Vt);
    attn_kernel<<<dim3(16, BB * EE), 256, 0, stream>>>(Qh, Ql, Kh, Kl, Vt, gate, AVh, AVl);
    proj_kernel<<<dim3(KSEL / 128, HH / 128, BB * EE), 256, 0, stream>>>(AVh, AVl, Woh, Wol,
                                                                         idx, out);
}